// Round 1
// baseline (646.334 us; speedup 1.0000x reference)
//
#include <hip/hip_runtime.h>
#include <hip/hip_bf16.h>

typedef float f4 __attribute__((ext_vector_type(4)));

constexpr int NN   = 4096;
constexpr int FINc = 512;
constexpr int FOUTc= 128;
constexpr int KHc  = 4;
constexpr int KFc  = 512;   // KHc * FOUTc
constexpr float ALPHA = 0.2f;

// ---------------- kernel 1: h = x @ W  (h[n][k*128+o]) ----------------
__global__ __launch_bounds__(256) void gemm_h_kernel(const float* __restrict__ x,
                                                     const float* __restrict__ W,
                                                     float* __restrict__ h) {
    __shared__ float xs[64][36];     // padded stride 36 to break bank aliasing
    __shared__ float wsm[32][64];
    const int t = threadIdx.x;
    const int n0 = blockIdx.y * 64;
    const int c0 = blockIdx.x * 64;          // 64-col tile, always within one head
    const int kblk  = c0 >> 7;
    const int obase = c0 & 127;
    const int tr = t >> 4, tc = t & 15;
    float acc[4][4] = {};
    for (int fc = 0; fc < FINc; fc += 32) {
        __syncthreads();
#pragma unroll
        for (int rep = 0; rep < 2; ++rep) {   // x tile 64x32
            int fidx = rep * 256 + t;
            int row = fidx >> 3, c4 = (fidx & 7) * 4;
            *(f4*)&xs[row][c4] = *(const f4*)&x[(size_t)(n0 + row) * FINc + fc + c4];
        }
#pragma unroll
        for (int rep = 0; rep < 2; ++rep) {   // W tile 32x64
            int fidx = rep * 256 + t;
            int ff = fidx >> 4, c4 = (fidx & 15) * 4;
            *(f4*)&wsm[ff][c4] =
                *(const f4*)&W[(size_t)kblk * 65536 + (size_t)(fc + ff) * 128 + obase + c4];
        }
        __syncthreads();
#pragma unroll
        for (int fg = 0; fg < 8; ++fg) {
            f4 xv[4], wv[4];
#pragma unroll
            for (int r = 0; r < 4; ++r) xv[r] = *(const f4*)&xs[tr * 4 + r][fg * 4];
#pragma unroll
            for (int f = 0; f < 4; ++f) wv[f] = *(const f4*)&wsm[fg * 4 + f][tc * 4];
#pragma unroll
            for (int r = 0; r < 4; ++r)
#pragma unroll
                for (int f = 0; f < 4; ++f)
#pragma unroll
                    for (int c = 0; c < 4; ++c)
                        acc[r][c] = fmaf(xv[r][f], wv[f][c], acc[r][c]);
        }
    }
#pragma unroll
    for (int r = 0; r < 4; ++r) {
        f4 v;
#pragma unroll
        for (int c = 0; c < 4; ++c) v[c] = acc[r][c];
        *(f4*)&h[(size_t)(n0 + tr * 4 + r) * KFc + c0 + tc * 4] = v;
    }
}

// ---------------- kernel 2: e_i[n,k], e_jT[k,n] ----------------
__global__ __launch_bounds__(256) void e_kernel(const float* __restrict__ h,
                                                const float* __restrict__ a,
                                                float* __restrict__ ei,
                                                float* __restrict__ ejT) {
    const int wid = threadIdx.x >> 6, lane = threadIdx.x & 63;
    const int n = blockIdx.x * 4 + wid;
#pragma unroll
    for (int k = 0; k < KHc; ++k) {
        float h0 = h[(size_t)n * KFc + k * FOUTc + lane];
        float h1 = h[(size_t)n * KFc + k * FOUTc + 64 + lane];
        float pi = h0 * a[k * 256 + lane]       + h1 * a[k * 256 + 64 + lane];
        float pj = h0 * a[k * 256 + 128 + lane] + h1 * a[k * 256 + 192 + lane];
#pragma unroll
        for (int off = 32; off; off >>= 1) {
            pi += __shfl_xor(pi, off);
            pj += __shfl_xor(pj, off);
        }
        if (lane == 0) { ei[n * KHc + k] = pi; ejT[k * NN + n] = pj; }
    }
}

// ---------------- kernel 3: per-row max and 1/denominator ----------------
__global__ __launch_bounds__(256) void rowstats_kernel(const int* __restrict__ adj,
                                                       const float* __restrict__ ei,
                                                       const float* __restrict__ ejT,
                                                       float* __restrict__ Mrow,
                                                       float* __restrict__ linv) {
    __shared__ unsigned char adjs[NN];
    __shared__ float wbuf[4];
    const int t = threadIdx.x;
    const int n = blockIdx.x;
    const int wid = t >> 6, lane = t & 63;
#pragma unroll
    for (int rep = 0; rep < 16; ++rep) {
        int m = rep * 256 + t;
        adjs[m] = (unsigned char)(adj[(size_t)n * NN + m] != 0);
    }
    __syncthreads();
    for (int k = 0; k < KHc; ++k) {
        const float eik = ei[n * KHc + k];
        const float* ej = &ejT[(size_t)k * NN];
        float mx = -1e30f;
        for (int rep = 0; rep < 16; ++rep) {
            int m = rep * 256 + t;
            if (adjs[m]) mx = fmaxf(mx, ej[m]);
        }
#pragma unroll
        for (int off = 32; off; off >>= 1) mx = fmaxf(mx, __shfl_xor(mx, off));
        if (lane == 0) wbuf[wid] = mx;
        __syncthreads();
        float bmax = fmaxf(fmaxf(wbuf[0], wbuf[1]), fmaxf(wbuf[2], wbuf[3]));
        float s0 = eik + bmax;
        float rowM = s0 > 0.f ? s0 : ALPHA * s0;   // lrelu monotonic => true row max
        float sum = 0.f;
        for (int rep = 0; rep < 16; ++rep) {
            int m = rep * 256 + t;
            if (adjs[m]) {
                float s = eik + ej[m];
                s = s > 0.f ? s : ALPHA * s;
                sum += __expf(s - rowM);
            }
        }
#pragma unroll
        for (int off = 32; off; off >>= 1) sum += __shfl_xor(sum, off);
        __syncthreads();
        if (lane == 0) wbuf[wid] = sum;
        __syncthreads();
        if (t == 0) {
            float bsum = wbuf[0] + wbuf[1] + wbuf[2] + wbuf[3];
            Mrow[n * KHc + k] = rowM;
            linv[n * KHc + k] = 1.0f / bsum;
        }
        __syncthreads();
    }
}

// ---------------- kernel 4: out = softmax(P) @ H per head ----------------
// block: 64 rows x 128 cols (one head); thread: 8x4 register tile
__global__ __launch_bounds__(256) void out_kernel(const int* __restrict__ adj,
                                                  const float* __restrict__ ei,
                                                  const float* __restrict__ ejT,
                                                  const float* __restrict__ Mrow,
                                                  const float* __restrict__ linv,
                                                  const float* __restrict__ h,
                                                  float* __restrict__ out) {
    __shared__ float p_lds[64][64];
    __shared__ float h_lds[64][128];
    __shared__ float eiL[64], ML[64], lL[64];
    const int t  = threadIdx.x;
    const int k  = blockIdx.x;
    const int n0 = blockIdx.y * 64;
    const int rg = t >> 5, cg = t & 31;
    if (t < 64) {
        eiL[t] = ei[(n0 + t) * KHc + k];
        ML[t]  = Mrow[(n0 + t) * KHc + k];
        lL[t]  = linv[(n0 + t) * KHc + k];
    }
    float acc[8][4] = {};
    const float* ej = &ejT[(size_t)k * NN];
    for (int mc = 0; mc < NN; mc += 64) {
        __syncthreads();
        {   // phase A: p tile 64(rows) x 64(m)
            const int j = t & 63;
            const float ejv = ej[mc + j];
            const int ibase = (t >> 6) * 16;
#pragma unroll
            for (int s = 0; s < 16; ++s) {
                int i = ibase + s;
                int av = adj[(size_t)(n0 + i) * NN + mc + j];
                float p = 0.f;
                if (av) {
                    float sc = eiL[i] + ejv;
                    sc = sc > 0.f ? sc : ALPHA * sc;
                    p = __expf(sc - ML[i]);
                }
                p_lds[i][j] = p;
            }
        }
#pragma unroll
        for (int rep = 0; rep < 8; ++rep) {   // stage H chunk 64 x 128
            int fidx = rep * 256 + t;
            int row = fidx >> 5, c4 = (fidx & 31) * 4;
            *(f4*)&h_lds[row][c4] =
                *(const f4*)&h[(size_t)(mc + row) * KFc + k * FOUTc + c4];
        }
        __syncthreads();
#pragma unroll
        for (int j4 = 0; j4 < 16; ++j4) {     // phase B: outer product
            f4 hv[4], pv[8];
#pragma unroll
            for (int jj = 0; jj < 4; ++jj) hv[jj] = *(const f4*)&h_lds[j4 * 4 + jj][cg * 4];
#pragma unroll
            for (int r = 0; r < 8; ++r) pv[r] = *(const f4*)&p_lds[rg * 8 + r][j4 * 4];
#pragma unroll
            for (int r = 0; r < 8; ++r)
#pragma unroll
                for (int jj = 0; jj < 4; ++jj)
#pragma unroll
                    for (int c = 0; c < 4; ++c)
                        acc[r][c] = fmaf(pv[r][jj], hv[jj][c], acc[r][c]);
        }
    }
#pragma unroll
    for (int r = 0; r < 8; ++r) {
        float sc = lL[rg * 8 + r];
        f4 v;
#pragma unroll
        for (int c = 0; c < 4; ++c) v[c] = acc[r][c] * sc;
        *(f4*)&out[(size_t)(n0 + rg * 8 + r) * KFc + k * FOUTc + cg * 4] = v;
    }
}

extern "C" void kernel_launch(void* const* d_in, const int* in_sizes, int n_in,
                              void* d_out, int out_size, void* d_ws, size_t ws_size,
                              hipStream_t stream) {
    const float* x   = (const float*)d_in[0];
    const int*   adj = (const int*)d_in[1];
    const float* W   = (const float*)d_in[2];
    const float* a   = (const float*)d_in[3];
    float* out = (float*)d_out;
    float* ws  = (float*)d_ws;

    float* h    = ws;                                  // N*KF      = 2097152 f
    float* ei   = ws + (size_t)NN * KFc;               // N*K       = 16384 f
    float* ejT  = ei + (size_t)NN * KHc;               // K*N
    float* Mrow = ejT + (size_t)NN * KHc;              // N*K
    float* linv = Mrow + (size_t)NN * KHc;             // N*K  (total ~8.65 MB)

    gemm_h_kernel<<<dim3(8, 64), 256, 0, stream>>>(x, W, h);
    e_kernel<<<NN / 4, 256, 0, stream>>>(h, a, ei, ejT);
    rowstats_kernel<<<NN, 256, 0, stream>>>(adj, ei, ejT, Mrow, linv);
    out_kernel<<<dim3(KHc, NN / 64), 256, 0, stream>>>(adj, ei, ejT, Mrow, linv, h, out);
}

// Round 2
// 217.760 us; speedup vs baseline: 2.9681x; 2.9681x over previous
//
#include <hip/hip_runtime.h>
#include <hip/hip_bf16.h>

typedef float f4 __attribute__((ext_vector_type(4)));
typedef unsigned short us8 __attribute__((ext_vector_type(8)));
typedef short bfrag __attribute__((ext_vector_type(8)));     // 8 bf16
typedef float f16v __attribute__((ext_vector_type(16)));

constexpr int NN   = 4096;
constexpr int FINc = 512;
constexpr int FOUTc= 128;
constexpr int KHc  = 4;
constexpr int KFc  = 512;   // KHc * FOUTc
constexpr float ALPHA = 0.2f;

static __device__ __forceinline__ unsigned short f2bf(float f) {
    unsigned u = __float_as_uint(f);
    unsigned r = (u + 0x7fffu + ((u >> 16) & 1u)) >> 16;   // RNE
    return (unsigned short)r;
}

// ---------------- kernel 0: adj -> bitmask ----------------
__global__ __launch_bounds__(256) void bits_kernel(const int* __restrict__ adj,
                                                   unsigned* __restrict__ bits) {
    size_t idx = (size_t)blockIdx.x * 256 + threadIdx.x;
    unsigned long long b = __ballot(adj[idx] != 0);
    int l = threadIdx.x & 63;
    if (l == 0)       bits[idx >> 5] = (unsigned)b;
    else if (l == 32) bits[idx >> 5] = (unsigned)(b >> 32);
}

// ---------------- kernel 1: h = x @ W  (h[n][k*128+o], fp32) ----------------
__global__ __launch_bounds__(256) void gemm_h_kernel(const float* __restrict__ x,
                                                     const float* __restrict__ W,
                                                     float* __restrict__ h) {
    __shared__ float xs[64][36];
    __shared__ float wsm[32][64];
    const int t = threadIdx.x;
    const int n0 = blockIdx.y * 64;
    const int c0 = blockIdx.x * 64;
    const int kblk  = c0 >> 7;
    const int obase = c0 & 127;
    const int tr = t >> 4, tc = t & 15;
    float acc[4][4] = {};
    for (int fc = 0; fc < FINc; fc += 32) {
        __syncthreads();
#pragma unroll
        for (int rep = 0; rep < 2; ++rep) {
            int fidx = rep * 256 + t;
            int row = fidx >> 3, c4 = (fidx & 7) * 4;
            *(f4*)&xs[row][c4] = *(const f4*)&x[(size_t)(n0 + row) * FINc + fc + c4];
        }
#pragma unroll
        for (int rep = 0; rep < 2; ++rep) {
            int fidx = rep * 256 + t;
            int ff = fidx >> 4, c4 = (fidx & 15) * 4;
            *(f4*)&wsm[ff][c4] =
                *(const f4*)&W[(size_t)kblk * 65536 + (size_t)(fc + ff) * 128 + obase + c4];
        }
        __syncthreads();
#pragma unroll
        for (int fg = 0; fg < 8; ++fg) {
            f4 xv[4], wv[4];
#pragma unroll
            for (int r = 0; r < 4; ++r) xv[r] = *(const f4*)&xs[tr * 4 + r][fg * 4];
#pragma unroll
            for (int f = 0; f < 4; ++f) wv[f] = *(const f4*)&wsm[fg * 4 + f][tc * 4];
#pragma unroll
            for (int r = 0; r < 4; ++r)
#pragma unroll
                for (int f = 0; f < 4; ++f)
#pragma unroll
                    for (int c = 0; c < 4; ++c)
                        acc[r][c] = fmaf(xv[r][f], wv[f][c], acc[r][c]);
        }
    }
#pragma unroll
    for (int r = 0; r < 4; ++r) {
        f4 v;
#pragma unroll
        for (int c = 0; c < 4; ++c) v[c] = acc[r][c];
        *(f4*)&h[(size_t)(n0 + tr * 4 + r) * KFc + c0 + tc * 4] = v;
    }
}

// ---------------- kernel 2: e_i[n,k], e_jT[k,n] ----------------
__global__ __launch_bounds__(256) void e_kernel(const float* __restrict__ h,
                                                const float* __restrict__ a,
                                                float* __restrict__ ei,
                                                float* __restrict__ ejT) {
    const int wid = threadIdx.x >> 6, lane = threadIdx.x & 63;
    const int n = blockIdx.x * 4 + wid;
#pragma unroll
    for (int k = 0; k < KHc; ++k) {
        float h0 = h[(size_t)n * KFc + k * FOUTc + lane];
        float h1 = h[(size_t)n * KFc + k * FOUTc + 64 + lane];
        float pi = h0 * a[k * 256 + lane]       + h1 * a[k * 256 + 64 + lane];
        float pj = h0 * a[k * 256 + 128 + lane] + h1 * a[k * 256 + 192 + lane];
#pragma unroll
        for (int off = 32; off; off >>= 1) {
            pi += __shfl_xor(pi, off);
            pj += __shfl_xor(pj, off);
        }
        if (lane == 0) { ei[n * KHc + k] = pi; ejT[k * NN + n] = pj; }
    }
}

// ---------------- kernel 3: per-row max and 1/denominator (bitmask) ----------------
__global__ __launch_bounds__(256) void rowstats_kernel(const unsigned* __restrict__ bits,
                                                       const float* __restrict__ ei,
                                                       const float* __restrict__ ejT,
                                                       float* __restrict__ Mrow,
                                                       float* __restrict__ linv) {
    __shared__ unsigned bw[128];
    __shared__ float wbuf[4];
    const int t = threadIdx.x;
    const int n = blockIdx.x;
    const int wid = t >> 6, lane = t & 63;
    if (t < 128) bw[t] = bits[(size_t)n * 128 + t];
    __syncthreads();
    for (int k = 0; k < KHc; ++k) {
        const float eik = ei[n * KHc + k];
        const float* ej = &ejT[(size_t)k * NN];
        float mx = -1e30f;
        for (int rep = 0; rep < 16; ++rep) {
            int m = rep * 256 + t;
            if ((bw[m >> 5] >> (m & 31)) & 1) mx = fmaxf(mx, ej[m]);
        }
#pragma unroll
        for (int off = 32; off; off >>= 1) mx = fmaxf(mx, __shfl_xor(mx, off));
        if (lane == 0) wbuf[wid] = mx;
        __syncthreads();
        float bmax = fmaxf(fmaxf(wbuf[0], wbuf[1]), fmaxf(wbuf[2], wbuf[3]));
        float s0 = eik + bmax;
        float rowM = s0 > 0.f ? s0 : ALPHA * s0;
        float sum = 0.f;
        for (int rep = 0; rep < 16; ++rep) {
            int m = rep * 256 + t;
            if ((bw[m >> 5] >> (m & 31)) & 1) {
                float s = eik + ej[m];
                s = s > 0.f ? s : ALPHA * s;
                sum += __expf(s - rowM);
            }
        }
#pragma unroll
        for (int off = 32; off; off >>= 1) sum += __shfl_xor(sum, off);
        __syncthreads();
        if (lane == 0) wbuf[wid] = sum;
        __syncthreads();
        if (t == 0) {
            float bsum = wbuf[0] + wbuf[1] + wbuf[2] + wbuf[3];
            Mrow[n * KHc + k] = rowM;
            linv[n * KHc + k] = 1.0f / bsum;
        }
        __syncthreads();
    }
}

// ---------------- kernel 4: h fp32 -> hT bf16 [k][col][m] ----------------
__global__ __launch_bounds__(256) void hcast_kernel(const float* __restrict__ h,
                                                    unsigned short* __restrict__ hT) {
    __shared__ float tile[64 * 64];
    const int t = threadIdx.x;
    const int c0 = blockIdx.x * 64;     // global col in [0,512)
    const int m0 = blockIdx.y * 64;
    const int lr = t >> 2, lcb = (t & 3) * 16;
#pragma unroll
    for (int j = 0; j < 4; ++j) {
        int c = lcb + j * 4;
        f4 v = *(const f4*)&h[(size_t)(m0 + lr) * KFc + c0 + c];
        *(f4*)&tile[lr * 64 + (c ^ ((lr & 15) << 2))] = v;    // swizzled store
    }
    __syncthreads();
    const int wc = t >> 2;            // local col 0..63
    const int mb = (t & 3) * 16;      // m chunk
    const int gk   = (c0 + wc) >> 7;
    const int gcol = (c0 + wc) & 127;
    alignas(16) unsigned short buf[16];
#pragma unroll
    for (int j = 0; j < 16; ++j) {
        int r = mb + j;
        float v = tile[r * 64 + (((wc & ~3) ^ ((r & 15) << 2)) | (wc & 3))];
        buf[j] = f2bf(v);
    }
    unsigned short* dst = &hT[((size_t)gk * 128 + gcol) * NN + m0 + mb];
    *(us8*)(dst)     = *(const us8*)&buf[0];
    *(us8*)(dst + 8) = *(const us8*)&buf[8];
}

// ---------------- kernel 5: out = softmax(P) @ H via MFMA bf16 ----------------
// block 256 thr, tile 64 rows x 128 cols (one head); wave = 32r x 64c (2 mfma col-tiles)
__global__ __launch_bounds__(256) void out_mfma_kernel(const unsigned* __restrict__ bits,
                                                       const float* __restrict__ ei,
                                                       const float* __restrict__ ejT,
                                                       const float* __restrict__ Mrow,
                                                       const float* __restrict__ linv,
                                                       const unsigned short* __restrict__ hT,
                                                       float* __restrict__ out) {
    __shared__ unsigned short P_lds[64 * 64];     // row stride 128B, swizzled
    __shared__ unsigned short Ht_lds[128 * 64];   // row stride 128B, swizzled
    __shared__ float eiL[64], ML[64], lL[64];
    const int t = threadIdx.x;
    const int k  = blockIdx.y;
    const int n0 = blockIdx.x * 64;
    const int lane = t & 63, wid = t >> 6;
    const int rowbase = (wid & 1) * 32;
    const int colbase = (wid >> 1) * 64;
    if (t < 64) {
        eiL[t] = ei[(n0 + t) * KHc + k];
        ML[t]  = Mrow[(n0 + t) * KHc + k];
        lL[t]  = linv[(n0 + t) * KHc + k];
    }
    f16v acc0 = {}; f16v acc1 = {};
    // P-gen mapping: row pi, 16 m-elems at pjb
    const int pi  = t >> 2;
    const int pjb = (t & 3) * 16;
    // H-stage mapping: row hr (= head-col), 64 bytes at hoff
    const int hr   = t >> 1;
    const int hoff = (t & 1) * 64;
    const unsigned short* hTk = hT + (size_t)k * FOUTc * NN;
    const float* ejp = &ejT[(size_t)k * NN];

    for (int mc = 0; mc < NN; mc += 64) {
        // ---- global loads (before barrier; only touch regs) ----
        f4 ejv[4];
#pragma unroll
        for (int j = 0; j < 4; ++j) ejv[j] = *(const f4*)&ejp[mc + pjb + j * 4];
        unsigned bw = bits[(size_t)(n0 + pi) * 128 + ((mc + pjb) >> 5)] >> (pjb & 16);
        us8 hg[4];
        {
            const unsigned short* src = &hTk[(size_t)hr * NN + mc + (hoff >> 1)];
#pragma unroll
            for (int c = 0; c < 4; ++c) hg[c] = *(const us8*)(src + c * 8);
        }
        __syncthreads();   // prior MFMA reads complete (and iter0: eiL ready)
        // ---- P tile 64x64 ----
        {
            float eiv = eiL[pi], Mv = ML[pi];
            alignas(16) unsigned short pv[16];
#pragma unroll
            for (int j = 0; j < 16; ++j) {
                float sc = eiv + ejv[j >> 2][j & 3];
                sc = fmaxf(sc, ALPHA * sc);               // leaky relu
                float p = ((bw >> j) & 1) ? __expf(sc - Mv) : 0.f;
                pv[j] = f2bf(p);
            }
            char* base = (char*)P_lds + pi * 128;
            int b0 = (pjb * 2)      ^ ((pi & 7) << 4);
            int b1 = (pjb * 2 + 16) ^ ((pi & 7) << 4);
            *(us8*)(base + b0) = *(const us8*)&pv[0];
            *(us8*)(base + b1) = *(const us8*)&pv[8];
        }
        // ---- Ht tile 128x64 ----
        {
            char* base = (char*)Ht_lds + hr * 128;
#pragma unroll
            for (int c = 0; c < 4; ++c) {
                int b = (hoff + c * 16) ^ ((hr & 7) << 4);
                *(us8*)(base + b) = hg[c];
            }
        }
        __syncthreads();
        // ---- MFMA: 4 k-steps of 16 ----
#pragma unroll
        for (int ks = 0; ks < 4; ++ks) {
            const int ar = rowbase + (lane & 31);
            const int kb = ks * 32 + (lane >> 5) * 16;
            bfrag af = *(const bfrag*)((const char*)P_lds + ar * 128 + (kb ^ ((ar & 7) << 4)));
            const int br0 = colbase + (lane & 31);
            bfrag bf0 = *(const bfrag*)((const char*)Ht_lds + br0 * 128 + (kb ^ ((br0 & 7) << 4)));
            acc0 = __builtin_amdgcn_mfma_f32_32x32x16_bf16(af, bf0, acc0, 0, 0, 0);
            const int br1 = br0 + 32;
            bfrag bf1 = *(const bfrag*)((const char*)Ht_lds + br1 * 128 + (kb ^ ((br1 & 7) << 4)));
            acc1 = __builtin_amdgcn_mfma_f32_32x32x16_bf16(af, bf1, acc1, 0, 0, 0);
        }
    }
    // ---- epilogue: scale by 1/l and store ----
    const int col = lane & 31;
    const int rb2 = rowbase + 4 * (lane >> 5);
#pragma unroll
    for (int reg = 0; reg < 16; ++reg) {
        int row = rb2 + (reg & 3) + 8 * (reg >> 2);
        float sc = lL[row];
        float* o = &out[(size_t)(n0 + row) * KFc + k * FOUTc + colbase + col];
        o[0]  = acc0[reg] * sc;
        o[32] = acc1[reg] * sc;
    }
}

extern "C" void kernel_launch(void* const* d_in, const int* in_sizes, int n_in,
                              void* d_out, int out_size, void* d_ws, size_t ws_size,
                              hipStream_t stream) {
    const float* x   = (const float*)d_in[0];
    const int*   adj = (const int*)d_in[1];
    const float* W   = (const float*)d_in[2];
    const float* a   = (const float*)d_in[3];
    float* out = (float*)d_out;
    char* ws = (char*)d_ws;

    float*          h    = (float*)ws;                        // 8 MB
    unsigned short* hT   = (unsigned short*)(ws + (8u << 20)); // 4 MB
    unsigned*       bits = (unsigned*)(ws + (12u << 20));      // 2 MB
    float*          ei   = (float*)(ws + (14u << 20));         // 64 KB
    float*          ejT  = ei + (size_t)NN * KHc;
    float*          Mrow = ejT + (size_t)NN * KHc;
    float*          linv = Mrow + (size_t)NN * KHc;

    bits_kernel<<<(NN * NN) / 256 / 1, 256, 0, stream>>>(adj, bits);
    gemm_h_kernel<<<dim3(8, 64), 256, 0, stream>>>(x, W, h);
    e_kernel<<<NN / 4, 256, 0, stream>>>(h, a, ei, ejT);
    rowstats_kernel<<<NN, 256, 0, stream>>>(bits, ei, ejT, Mrow, linv);
    hcast_kernel<<<dim3(8, 64), 256, 0, stream>>>(h, hT);
    out_mfma_kernel<<<dim3(NN / 64, KHc), 256, 0, stream>>>(bits, ei, ejT, Mrow, linv, hT, out);
}

// Round 3
// 129.418 us; speedup vs baseline: 4.9942x; 1.6826x over previous
//
#include <hip/hip_runtime.h>
#include <hip/hip_bf16.h>

typedef float f4 __attribute__((ext_vector_type(4)));
typedef unsigned short us8 __attribute__((ext_vector_type(8)));
typedef short bfrag __attribute__((ext_vector_type(8)));     // 8 bf16
typedef float f16v __attribute__((ext_vector_type(16)));

constexpr int NN   = 4096;
constexpr int FINc = 512;
constexpr int FOUTc= 128;
constexpr int KHc  = 4;
constexpr int KFc  = 512;
constexpr float ALPHA = 0.2f;
constexpr float LOG2E = 1.44269504088896340736f;

static __device__ __forceinline__ unsigned short f2bf(float f) {
    unsigned u = __float_as_uint(f);
    return (unsigned short)((u + 0x7fffu + ((u >> 16) & 1u)) >> 16);   // RNE
}
static __device__ __forceinline__ float bf2f(unsigned short u) {
    return __uint_as_float(((unsigned)u) << 16);
}

// ---------------- kernel 0: adj -> bitmask ----------------
__global__ __launch_bounds__(256) void bits_kernel(const int* __restrict__ adj,
                                                   unsigned* __restrict__ bits) {
    size_t idx = (size_t)blockIdx.x * 256 + threadIdx.x;
    unsigned long long b = __ballot(adj[idx] != 0);
    int l = threadIdx.x & 63;
    if (l == 0)       bits[idx >> 5] = (unsigned)b;
    else if (l == 32) bits[idx >> 5] = (unsigned)(b >> 32);
}

// ---------------- kernel 1: cast x -> xb (bf16), W -> WbT[k][o][f] (bf16) ----------------
__global__ __launch_bounds__(256) void prep_kernel(const float* __restrict__ x,
                                                   const float* __restrict__ W,
                                                   unsigned short* __restrict__ xb,
                                                   unsigned short* __restrict__ WbT) {
    const int b = blockIdx.x, t = threadIdx.x;
    if (b < 1024) {                       // x: 2M elements, 8 per thread
        size_t base = ((size_t)b * 256 + t) * 8;
        f4 v0 = *(const f4*)&x[base];
        f4 v1 = *(const f4*)&x[base + 4];
        us8 o;
#pragma unroll
        for (int j = 0; j < 4; ++j) { o[j] = f2bf(v0[j]); o[4 + j] = f2bf(v1[j]); }
        *(us8*)&xb[base] = o;
    } else {                              // W transpose: 512 threads, one per (k,o)
        int idx = (b - 1024) * 256 + t;
        int k = idx >> 7, o = idx & 127;
        const float* src = &W[(size_t)k * 65536 + o];        // stride 128 over f
        unsigned short* dst = &WbT[((size_t)k * 128 + o) * FINc];
        for (int f8 = 0; f8 < FINc; f8 += 8) {
            us8 v;
#pragma unroll
            for (int j = 0; j < 8; ++j) v[j] = f2bf(src[(size_t)(f8 + j) * 128]);
            *(us8*)&dst[f8] = v;
        }
    }
}

// ---------------- kernel 2: hT[k][o][m] = (x @ W) bf16 via MFMA ----------------
__global__ __launch_bounds__(256) void gemmh_kernel(const unsigned short* __restrict__ xb,
                                                    const unsigned short* __restrict__ WbT,
                                                    unsigned short* __restrict__ hT) {
    __shared__ char Ax[64 * 128];
    __shared__ char Bx[64 * 128];
    const int t = threadIdx.x, wid = t >> 6, lane = t & 63;
    const int c0 = blockIdx.x * 64, n0 = blockIdx.y * 64;
    const int head = c0 >> 7, ob = c0 & 127;
    const int srow = t >> 2, sseg = t & 3;
    const unsigned short* asrc = &xb[(size_t)(n0 + srow) * FINc + sseg * 16];
    const unsigned short* bsrc = &WbT[((size_t)(head * 128 + ob + srow)) * FINc + sseg * 16];
    const int rowbase = (wid & 1) * 32, colbase = (wid >> 1) * 32;
    f16v acc = {};
    for (int fc = 0; fc < FINc; fc += 64) {
        us8 a0 = *(const us8*)(asrc + fc), a1 = *(const us8*)(asrc + fc + 8);
        us8 b0 = *(const us8*)(bsrc + fc), b1 = *(const us8*)(bsrc + fc + 8);
        __syncthreads();
        {
            int byt = (sseg * 32) ^ ((srow & 7) << 4);
            char* pa = Ax + srow * 128;
            *(us8*)(pa + byt) = a0;  *(us8*)(pa + (byt ^ 16)) = a1;
            char* pb = Bx + srow * 128;
            *(us8*)(pb + byt) = b0;  *(us8*)(pb + (byt ^ 16)) = b1;
        }
        __syncthreads();
#pragma unroll
        for (int ks = 0; ks < 4; ++ks) {
            int kb = ks * 32 + ((lane >> 5) << 4);
            int ar = rowbase + (lane & 31);
            bfrag af = *(const bfrag*)(Ax + ar * 128 + (kb ^ ((ar & 7) << 4)));
            int bc = colbase + (lane & 31);
            bfrag bf = *(const bfrag*)(Bx + bc * 128 + (kb ^ ((bc & 7) << 4)));
            acc = __builtin_amdgcn_mfma_f32_32x32x16_bf16(af, bf, acc, 0, 0, 0);
        }
    }
    // epilogue: acc -> LDS (transposed access) -> hT[k][col][m]
    __syncthreads();
#pragma unroll
    for (int reg = 0; reg < 16; ++reg) {
        int row = rowbase + (reg & 3) + 8 * (reg >> 2) + 4 * (lane >> 5);
        int col = colbase + (lane & 31);
        *(unsigned short*)(Ax + row * 128 + ((col * 2) ^ ((row & 7) << 4))) = f2bf(acc[reg]);
    }
    __syncthreads();
    {
        int col = t >> 2, mseg = (t & 3) * 16;
        alignas(16) unsigned short buf[16];
#pragma unroll
        for (int j = 0; j < 16; ++j) {
            int r = mseg + j;
            buf[j] = *(const unsigned short*)(Ax + r * 128 + ((col * 2) ^ ((r & 7) << 4)));
        }
        unsigned short* dst = &hT[((size_t)(head * 128 + ob + col)) * NN + n0 + mseg];
        *(us8*)dst       = *(const us8*)&buf[0];
        *(us8*)(dst + 8) = *(const us8*)&buf[8];
    }
}

// ---------------- kernel 3: ei[n,k], ejT[k,n] (pre-scaled by log2e) ----------------
__global__ __launch_bounds__(256) void e2_kernel(const unsigned short* __restrict__ hT,
                                                 const float* __restrict__ a,
                                                 float* __restrict__ ei,
                                                 float* __restrict__ ejT) {
    __shared__ float as[128], ad[128];
    __shared__ float pim[4][64], pjm[4][64];
    const int t = threadIdx.x;
    const int k = blockIdx.x >> 6;
    const int m0 = (blockIdx.x & 63) * 64;
    if (t < 128) as[t] = a[k * 256 + t] * LOG2E;
    else         ad[t - 128] = a[k * 256 + t] * LOG2E;
    __syncthreads();
    const int ml = t & 63, q = t >> 6;
    const unsigned short* src = &hT[((size_t)k * FOUTc + q * 32) * NN + m0 + ml];
    float si = 0.f, sj = 0.f;
#pragma unroll 8
    for (int c = 0; c < 32; ++c) {
        float v = bf2f(src[(size_t)c * NN]);
        si += v * as[q * 32 + c];
        sj += v * ad[q * 32 + c];
    }
    pim[q][ml] = si; pjm[q][ml] = sj;
    __syncthreads();
    if (t < 64) {
        ei[(m0 + t) * KHc + k]   = pim[0][t] + pim[1][t] + pim[2][t] + pim[3][t];
        ejT[(size_t)k * NN + m0 + t] = pjm[0][t] + pjm[1][t] + pjm[2][t] + pjm[3][t];
    }
}

// ---------------- kernel 4: out = softmax(P) @ H, denom fused ----------------
// 32 rows x 128 cols per block, 512 blocks (2/CU), XCD-chunked swizzle
__global__ __launch_bounds__(256) void out_mfma_kernel(const unsigned* __restrict__ bits,
                                                       const float* __restrict__ ei,
                                                       const float* __restrict__ ejT,
                                                       const unsigned short* __restrict__ hT,
                                                       float* __restrict__ out) {
    __shared__ char P_lds[32 * 128];
    __shared__ char Ht_lds[128 * 128];
    __shared__ float eiL[32];
    __shared__ float lsum[32];
    const int bid = blockIdx.x;
    const int nb  = (bid & 7) * 64 + (bid >> 3);   // bijective: 512 = 8*64
    const int k   = nb >> 7;
    const int n0  = (nb & 127) * 32;
    const int t = threadIdx.x, lane = t & 63, wid = t >> 6;
    const int colbase = wid * 32;
    const int pi = t >> 3, pjb = (t & 7) * 8;
    const int hr = t >> 1, hoff = (t & 1) * 64;
    if (t < 32) eiL[t] = ei[(n0 + t) * KHc + k];
    const unsigned short* hTk = hT + (size_t)k * FOUTc * NN;
    const float* ejp = &ejT[(size_t)k * NN];
    const unsigned* brow = &bits[(size_t)(n0 + pi) * 128];
    f16v acc = {};
    float psum = 0.f;

    for (int mc = 0; mc < NN; mc += 64) {
        // prefetch to regs (overlaps barrier)
        f4 ejv0 = *(const f4*)&ejp[mc + pjb];
        f4 ejv1 = *(const f4*)&ejp[mc + pjb + 4];
        unsigned bw = brow[(mc + pjb) >> 5] >> (pjb & 24);
        us8 hg[4];
        const unsigned short* src = &hTk[(size_t)hr * NN + mc + (hoff >> 1)];
#pragma unroll
        for (int c = 0; c < 4; ++c) hg[c] = *(const us8*)(src + c * 8);
        __syncthreads();
        // P tile 32x64 (values = exp2(lrelu-scaled score)), fp32 row-sum kept
        {
            float eiv = eiL[pi];
            float p[8];
#pragma unroll
            for (int j = 0; j < 8; ++j) {
                float sc = eiv + (j < 4 ? ejv0[j] : ejv1[j - 4]);
                sc = fmaxf(sc, ALPHA * sc);
                float pp = exp2f(sc);
                pp = ((bw >> j) & 1) ? pp : 0.f;
                p[j] = pp;
                psum += pp;
            }
            union { unsigned u[4]; us8 v; } pk;
#pragma unroll
            for (int j = 0; j < 4; ++j) {
                float2 fp; fp.x = p[2 * j]; fp.y = p[2 * j + 1];
                __hip_bfloat162 b2 = __float22bfloat162_rn(fp);
                pk.u[j] = *reinterpret_cast<unsigned*>(&b2);
            }
            *(us8*)(P_lds + pi * 128 + ((pjb * 2) ^ ((pi & 7) << 4))) = pk.v;
        }
        // Ht tile 128x64
        {
            char* base = Ht_lds + hr * 128;
#pragma unroll
            for (int c = 0; c < 4; ++c) {
                int b = (hoff + c * 16) ^ ((hr & 7) << 4);
                *(us8*)(base + b) = hg[c];
            }
        }
        __syncthreads();
#pragma unroll
        for (int ks = 0; ks < 4; ++ks) {
            int kb = ks * 32 + ((lane >> 5) << 4);
            int ar = lane & 31;
            bfrag af = *(const bfrag*)(P_lds + ar * 128 + (kb ^ ((ar & 7) << 4)));
            int bc = colbase + (lane & 31);
            bfrag bf = *(const bfrag*)(Ht_lds + bc * 128 + (kb ^ ((bc & 7) << 4)));
            acc = __builtin_amdgcn_mfma_f32_32x32x16_bf16(af, bf, acc, 0, 0, 0);
        }
    }
    // fused denominator: reduce 8 threads per row
    psum += __shfl_xor(psum, 1);
    psum += __shfl_xor(psum, 2);
    psum += __shfl_xor(psum, 4);
    if ((t & 7) == 0) lsum[pi] = psum;
    __syncthreads();
    if (t < 32) lsum[t] = 1.0f / lsum[t];
    __syncthreads();
#pragma unroll
    for (int reg = 0; reg < 16; ++reg) {
        int row = (reg & 3) + 8 * (reg >> 2) + 4 * (lane >> 5);
        out[(size_t)(n0 + row) * KFc + k * FOUTc + colbase + (lane & 31)] = acc[reg] * lsum[row];
    }
}

extern "C" void kernel_launch(void* const* d_in, const int* in_sizes, int n_in,
                              void* d_out, int out_size, void* d_ws, size_t ws_size,
                              hipStream_t stream) {
    const float* x   = (const float*)d_in[0];
    const int*   adj = (const int*)d_in[1];
    const float* W   = (const float*)d_in[2];
    const float* a   = (const float*)d_in[3];
    float* out = (float*)d_out;
    char* ws = (char*)d_ws;

    unsigned short* hT   = (unsigned short*)ws;                 // 4 MB
    unsigned short* xb   = (unsigned short*)(ws + (4u << 20));  // 4 MB
    unsigned short* WbT  = (unsigned short*)(ws + (8u << 20));  // 0.5 MB
    unsigned*       bits = (unsigned*)(ws + (9u << 20));        // 2 MB
    float*          ei   = (float*)(ws + (11u << 20));          // 64 KB
    float*          ejT  = ei + (size_t)NN * KHc;               // 64 KB

    bits_kernel<<<(NN * NN) / 256, 256, 0, stream>>>(adj, bits);
    prep_kernel<<<1026, 256, 0, stream>>>(x, W, xb, WbT);
    gemmh_kernel<<<dim3(8, 64), 256, 0, stream>>>(xb, WbT, hT);
    e2_kernel<<<256, 256, 0, stream>>>(hT, a, ei, ejT);
    out_mfma_kernel<<<512, 256, 0, stream>>>(bits, ei, ejT, hT, out);
}